// Round 6
// baseline (665.918 us; speedup 1.0000x reference)
//
#include <hip/hip_runtime.h>
#include <cstdint>
#include <cstddef>

// QRNN fused pipeline for MI355X (gfx950).
// B=32, S=2048, D_in=512, D_model=1024, D_mlp=1024, n_cls=128.
//
// ws layout (bytes): U bf16 [2048][1024] @0 (4MB) | Fagg @4MB | Zagg @6MB |
//   h @8MB | q0 @8MB+256K | q1 @8MB+512K | zero page @12MB (4KB) | xb bf16 @16MB (64MB)
//
//  1) prologue: pack_x (fp32->bf16) + pack_u (LDS transpose) + bias preload, one kernel
//  2) qrnn_main<USE_BF>: per (b, 256-step chunk, 64 d): 256x128 MFMA tile, 257-row A
//     window, precomputed voffsets vs single ws base (kt advance folds to immediates),
//     two MFMA passes (W rows+1, V rows+0), in-register activations, segmented scan.
//     Templated so the hot (bf16) variant contains NO fp32 fallback code -> fits the
//     128-reg/wave budget (64 acc AGPR + <64 VGPR) without scratch spill.
//  3) head: K-split o-gate + 8-chunk combine -> h
//  4) mlp x3 as K-split atomic GEMV (ReLU applied on consumer's input read)

typedef __attribute__((ext_vector_type(8))) short short8;
typedef __attribute__((ext_vector_type(4))) float f32x4;

#define ZERO_OFF_E 6291456u    // 12MB / 2
#define XB_OFF_E   8388608u    // 16MB / 2

__device__ __forceinline__ unsigned short f2bf(float f) {
  unsigned int u = __float_as_uint(f);
  u += 0x7fffu + ((u >> 16) & 1u);
  return (unsigned short)(u >> 16);
}

__device__ __forceinline__ void gload_lds16(const void* g, void* l) {
  __builtin_amdgcn_global_load_lds(
      (const __attribute__((address_space(1))) unsigned int*)g,
      (__attribute__((address_space(3))) unsigned int*)l, 16, 0, 0);
}

__device__ __forceinline__ float sigmoidf_fast(float x) {
  return 1.f / (1.f + __expf(-x));
}
__device__ __forceinline__ float tanhf_fast(float x) {
  float a = fabsf(x);
  float e = __expf(-2.f * a);
  float t = (1.f - e) / (1.f + e);
  return copysignf(t, x);
}

// ---------------- prologue: pack_x + pack_u + bias preload ----------------
// grid 33408: [0,32768) pack_x; [32768,33280) pack_u; [33280,33408) init
__global__ void prologue_kernel(const float* __restrict__ x, const float* __restrict__ W,
                                const float* __restrict__ V,
                                const float* __restrict__ b0, const float* __restrict__ b1,
                                const float* __restrict__ b2,
                                unsigned short* __restrict__ xb, unsigned short* __restrict__ U,
                                float* __restrict__ q0, float* __restrict__ q1,
                                float* __restrict__ out) {
  __shared__ float T[64 * 65];
  const int bx = blockIdx.x;
  if (bx < 32768) {
    int gid = bx * 256 + threadIdx.x;
    float4 v = ((const float4*)x)[gid];
    ushort4 o;
    o.x = f2bf(v.x); o.y = f2bf(v.y); o.z = f2bf(v.z); o.w = f2bf(v.w);
    ((ushort4*)xb)[gid] = o;
  } else if (bx < 33280) {
    const int u = bx - 32768;
    const int j0 = (u & 31) * 64;
    const int k0 = (u >> 5) * 64;
    const int jl = threadIdx.x & 63;
    const int q  = threadIdx.x >> 6;
    const float* src = (k0 < 512) ? (W + (size_t)k0 * 3072) : (V + (size_t)(k0 - 512) * 3072);
#pragma unroll 4
    for (int i = 0; i < 16; ++i) {
      int kl = q * 16 + i;
      T[kl * 65 + jl] = src[(size_t)kl * 3072 + j0 + jl];
    }
    __syncthreads();
    const int kl = threadIdx.x & 63;
#pragma unroll 4
    for (int i = 0; i < 16; ++i) {
      int jj = q * 16 + i;
      U[(size_t)(j0 + jj) * 1024 + k0 + kl] = f2bf(T[kl * 65 + jj]);
    }
  } else {
    int gid = (bx - 33280) * 256 + threadIdx.x;   // 32768
    q0[gid] = b0[gid & 1023];
    q1[gid] = b1[gid & 1023];
    if (gid < 4096) out[gid] = b2[gid & 127];
  }
}

// ---------------- main: 256x128 MFMA tile + fused scan ----------------
// grid (16 dt, 8 cj, 32 b), block 512 (4x2 waves of 64x64)
template <bool USE_BF>
__global__ __launch_bounds__(512, 4) void qrnn_main(
    const unsigned short* __restrict__ wsb, const float* __restrict__ xf,
    const float* __restrict__ Vb,
    float* __restrict__ Fagg, float* __restrict__ Zagg) {
  __shared__ __align__(16) char smem[65664];
  char* As = smem;             // [257][128B] = 32896
  char* Us = smem + 32896;     // [2][128][128B] = 32768

  const int dt = blockIdx.x;
  const int cj = blockIdx.y;
  const int b  = blockIdx.z;
  const int tid = threadIdx.x;
  const int lane = tid & 63;
  const int wid  = tid >> 6;          // 0..7
  const int wm = wid >> 1, wn = wid & 1;   // 4m x 2n wave grid
  const int s0 = cj * 256;

  f32x4 acc[4][4];
#pragma unroll
  for (int i = 0; i < 4; ++i)
#pragma unroll
    for (int j = 0; j < 4; ++j) acc[i][j] = f32x4{0.f, 0.f, 0.f, 0.f};

  const int mrow = wm * 64 + (lane & 15);   // 0..255
  const int ncol = wn * 64 + (lane & 15);   // 0..127
  const int rloc = lane >> 3;     // 0..7
  const int pc   = lane & 7;      // phys chunk
  const int c0   = lane >> 4;     // 0..3

  // ---- precomputed staging voffsets (elements, vs wsb base) ----
  unsigned voffA[4], voffU[4];
  unsigned voffA4 = 0;
#pragma unroll
  for (int p = 0; p < 4; ++p) {
    int rr = wid * 32 + p * 8 + rloc;     // 0..255
    int c = pc ^ (rr & 7);
    int sg = s0 - 1 + rr;
    voffA[p] = (sg >= 0)
        ? (XB_OFF_E + (unsigned)(b * 2048 + sg) * 512u + (unsigned)(c * 8))
        : (ZERO_OFF_E + (unsigned)(pc * 8));
    int half = rr >> 7, col = rr & 127;
    int j = (col < 64) ? (dt * 64 + col) : (1024 + dt * 64 + (col - 64));
    voffU[p] = (unsigned)(j * 1024 + half * 512 + c * 8);
  }
  if (tid < 8)
    voffA4 = XB_OFF_E + (unsigned)(b * 2048 + s0 + 255) * 512u + (unsigned)(tid * 8);

  // ---- precomputed fragment LDS pointers ----
  const char* pA[2][2];
  const char* pU[2];
#pragma unroll
  for (int h2 = 0; h2 < 2; ++h2) {
    int rr = mrow + 1 - h2;
#pragma unroll
    for (int kb = 0; kb < 2; ++kb)
      pA[h2][kb] = As + rr * 128 + (((kb * 4 + c0) ^ (rr & 7)) << 4);
  }
#pragma unroll
  for (int kb = 0; kb < 2; ++kb)
    pU[kb] = Us + ncol * 128 + (((kb * 4 + c0) ^ (ncol & 7)) << 4);

  const unsigned short* base = wsb;   // advances 64 elems (128B) per kt -> imm offsets

#pragma unroll
  for (int kt = 0; kt < 8; ++kt) {
    __syncthreads();
    if constexpr (USE_BF) {
#pragma unroll
      for (int p = 0; p < 4; ++p)
        gload_lds16(base + voffA[p], As + (wid * 32 + p * 8) * 128);
      if (tid < 8)
        gload_lds16(base + voffA4, As + 256 * 128);
#pragma unroll
      for (int p = 0; p < 4; ++p)
        gload_lds16(base + voffU[p], Us + (wid * 32 + p * 8) * 128);
    } else {
      // fp32 fallback: load + convert through VGPRs (cold variant only)
#pragma unroll
      for (int p = 0; p < 4; ++p) {
        int rr = (tid >> 3) + p * 64;
        int fc = tid & 7;
        int s = s0 - 1 + rr;
        uint4 v = make_uint4(0u, 0u, 0u, 0u);
        if (s >= 0) {
          const float* src = xf + (((size_t)b * 2048 + s) << 9) + kt * 64 + fc * 8;
          float4 a0 = *(const float4*)src;
          float4 a1 = *(const float4*)(src + 4);
          v.x = (unsigned)f2bf(a0.x) | ((unsigned)f2bf(a0.y) << 16);
          v.y = (unsigned)f2bf(a0.z) | ((unsigned)f2bf(a0.w) << 16);
          v.z = (unsigned)f2bf(a1.x) | ((unsigned)f2bf(a1.y) << 16);
          v.w = (unsigned)f2bf(a1.z) | ((unsigned)f2bf(a1.w) << 16);
        }
        *(uint4*)(As + rr * 128 + ((fc ^ (rr & 7)) << 4)) = v;
      }
      if (tid < 8) {
        const float* src = xf + (((size_t)b * 2048 + s0 + 255) << 9) + kt * 64 + tid * 8;
        float4 a0 = *(const float4*)src;
        float4 a1 = *(const float4*)(src + 4);
        uint4 v;
        v.x = (unsigned)f2bf(a0.x) | ((unsigned)f2bf(a0.y) << 16);
        v.y = (unsigned)f2bf(a0.z) | ((unsigned)f2bf(a0.w) << 16);
        v.z = (unsigned)f2bf(a1.x) | ((unsigned)f2bf(a1.y) << 16);
        v.w = (unsigned)f2bf(a1.z) | ((unsigned)f2bf(a1.w) << 16);
        *(uint4*)(As + 256 * 128 + (tid << 4)) = v;
      }
#pragma unroll
      for (int p = 0; p < 4; ++p) {
        int fc = tid & 7;
        uint4 v = *(const uint4*)(wsb + voffU[p] + kt * 64);
        *(uint4*)(Us + (wid * 32 + p * 8 + rloc) * 128 + (((fc ^ ((wid * 32 + p * 8 + rloc) & 7)) ^ (pc ^ ((wid * 32 + p * 8 + rloc) & 7))) << 4) + (pc << 4)) = v;
      }
    }
    __syncthreads();
    // ---- MFMA: 2 passes (h2) x 2 k-blocks, streamed A fragments ----
#pragma unroll
    for (int h2 = 0; h2 < 2; ++h2) {
#pragma unroll
      for (int kb = 0; kb < 2; ++kb) {
        const char* pa = pA[h2][kb];
        const char* pu = pU[kb] + h2 * 16384;
        short8 bfr[4];
#pragma unroll
        for (int nt = 0; nt < 4; ++nt)
          bfr[nt] = *(const short8*)(pu + nt * 2048);
#pragma unroll
        for (int mt = 0; mt < 4; ++mt) {
          short8 afr = *(const short8*)(pa + mt * 2048);
#pragma unroll
          for (int nt = 0; nt < 4; ++nt)
            acc[mt][nt] = __builtin_amdgcn_mfma_f32_16x16x32_bf16(afr, bfr[nt], acc[mt][nt], 0, 0, 0);
        }
      }
    }
    base += 64;
  }

  // ---- fused activations + scan (4 phases of 64 timesteps) ----
  float* fA   = (float*)smem;            // [64][68]
  float* tzA  = (float*)(smem + 17408);  // [64][68]
  float* segF = (float*)(smem + 34816);  // [8][64]
  float* segZ = (float*)(smem + 36864);  // [8][64]

  const int d = tid & 63;
  const int dl = lane & 15;
  float vb[4];
#pragma unroll
  for (int nt = 0; nt < 4; ++nt)
    vb[nt] = Vb[wn * 1024 + dt * 64 + nt * 16 + dl];

  float F_run = 1.f, Z_run = 0.f;

  for (int ph = 0; ph < 4; ++ph) {
    __syncthreads();
    if (wm == ph) {
      float* dst = (wn == 0) ? fA : tzA;
#pragma unroll
      for (int mt = 0; mt < 4; ++mt)
#pragma unroll
        for (int nt = 0; nt < 4; ++nt)
#pragma unroll
          for (int rg = 0; rg < 4; ++rg) {
            int t = mt * 16 + ((lane >> 4) << 2) + rg;   // 0..63 phase-local
            int c = nt * 16 + dl;
            float v = acc[mt][nt][rg] + vb[nt];
            v = (wn == 0) ? sigmoidf_fast(v) : tanhf_fast(v);
            dst[t * 68 + c] = v;
          }
    }
    __syncthreads();
    {
      int seg = tid >> 6;   // 0..7, 8 steps each
      float F = 1.f, Z = 0.f;
#pragma unroll
      for (int i = 0; i < 8; ++i) {
        int t = seg * 8 + i;
        float f  = fA[t * 68 + d];
        float tz = tzA[t * 68 + d];
        float z = (1.f - f) * tz;
        Z = f * Z + z;
        F *= f;
      }
      segF[seg * 64 + d] = F;
      segZ[seg * 64 + d] = Z;
    }
    __syncthreads();
    if (tid < 64) {
#pragma unroll
      for (int sgi = 0; sgi < 8; ++sgi) {
        float Fs = segF[sgi * 64 + tid], Zs = segZ[sgi * 64 + tid];
        Z_run = Fs * Z_run + Zs;
        F_run *= Fs;
      }
    }
  }
  if (tid < 64) {
    size_t o = (((size_t)b * 8 + cj) << 10) + dt * 64 + tid;
    Fagg[o] = F_run;
    Zagg[o] = Z_run;
  }
}

// ---------------- head: K-split o-gate + 8-chunk combine ----------------
// grid (16 dtile, 32 b), block 256 = 64 d x 4 k-segments
__global__ void head_kernel(const float* __restrict__ x, const float* __restrict__ W,
                            const float* __restrict__ V, const float* __restrict__ Vb,
                            const float* __restrict__ Fagg, const float* __restrict__ Zagg,
                            float* __restrict__ h) {
  __shared__ float red[4][64];
  const int dl = threadIdx.x & 63;
  const int w  = threadIdx.x >> 6;
  const int d = blockIdx.x * 64 + dl;
  const int b = blockIdx.y;

  const float* xl = x + ((size_t)b * 2048 + 2047) * 512;
  const float* xp = xl - 512;
  const float* Wc = W + 2048 + d;
  const float* Vc = V + 2048 + d;
  float po = 0.f;
  const int k0 = w * 128;
#pragma unroll 8
  for (int k = k0; k < k0 + 128; ++k) {
    po += xl[k] * Wc[(size_t)k * 3072];
    po += xp[k] * Vc[(size_t)k * 3072];
  }
  red[w][dl] = po;
  __syncthreads();
  if (w == 0) {
    po = red[0][dl] + red[1][dl] + red[2][dl] + red[3][dl] + Vb[2048 + d];
    float c = 0.f;
#pragma unroll
    for (int j = 0; j < 8; ++j) {
      size_t o = (((size_t)b * 8 + j) << 10) + d;
      c = Fagg[o] * c + Zagg[o];
    }
    h[((size_t)b << 10) + d] = c * sigmoidf_fast(po);
  }
}

// ---------------- MLP: K-split atomic GEMV (ReLU on input) ----------------
// grid (N/64, B, 4 ksplit), block 256 = 64 n x 4 waves
__global__ void mlp_atomic_kernel(const float* __restrict__ in, const float* __restrict__ Wt,
                                  float* __restrict__ out, int K, int N, int relu_in) {
  __shared__ float red[4][64];
  const int nl = threadIdx.x & 63;
  const int w  = threadIdx.x >> 6;
  const int n = blockIdx.x * 64 + nl;
  const int b = blockIdx.y;
  const int k0 = blockIdx.z * (K >> 2) + w * (K >> 4);
  const float* row = in + (size_t)b * K;
  const float* Wc = Wt + n;
  float s = 0.f;
#pragma unroll 8
  for (int k = k0; k < k0 + (K >> 4); ++k) {
    float v = row[k];
    if (relu_in) v = fmaxf(v, 0.f);
    s += v * Wc[(size_t)k * N];
  }
  red[w][nl] = s;
  __syncthreads();
  if (w == 0) {
    s = red[0][nl] + red[1][nl] + red[2][nl] + red[3][nl];
    atomicAdd(&out[(size_t)b * N + n], s);
  }
}

extern "C" void kernel_launch(void* const* d_in, const int* in_sizes, int n_in,
                              void* d_out, int out_size, void* d_ws, size_t ws_size,
                              hipStream_t stream) {
  const float* x  = (const float*)d_in[0];
  const float* W  = (const float*)d_in[1];
  const float* V  = (const float*)d_in[2];
  const float* Vb = (const float*)d_in[3];
  const float* W0 = (const float*)d_in[4];
  const float* b0 = (const float*)d_in[5];
  const float* W1 = (const float*)d_in[6];
  const float* b1 = (const float*)d_in[7];
  const float* W2 = (const float*)d_in[8];
  const float* b2 = (const float*)d_in[9];

  char* ws = (char*)d_ws;
  unsigned short* U = (unsigned short*)(ws);                              // 4 MiB
  float* Fagg = (float*)(ws + (size_t)4 * 1024 * 1024);                   // 1 MiB used
  float* Zagg = (float*)(ws + (size_t)6 * 1024 * 1024);                   // 1 MiB used
  float* h    = (float*)(ws + (size_t)8 * 1024 * 1024);                   // 128 KiB
  float* q0   = (float*)(ws + (size_t)8 * 1024 * 1024 + 256 * 1024);
  float* q1   = (float*)(ws + (size_t)8 * 1024 * 1024 + 512 * 1024);
  char*  zpg  = ws + (size_t)12 * 1024 * 1024;                            // 4 KiB zeros
  unsigned short* xb = (unsigned short*)(ws + (size_t)16 * 1024 * 1024);  // 64 MiB

  const size_t need_bf = (size_t)16 * 1024 * 1024 + (size_t)67108864;
  int use_bf = (ws_size >= need_bf) ? 1 : 0;   // constant across calls -> graph-safe

  hipMemsetAsync(zpg, 0, 4096, stream);
  prologue_kernel<<<33408, 256, 0, stream>>>(x, W, V, b0, b1, b2, xb, U, q0, q1,
                                             (float*)d_out);
  if (use_bf)
    qrnn_main<true><<<dim3(16, 8, 32), 512, 0, stream>>>((const unsigned short*)ws, x,
                                                         Vb, Fagg, Zagg);
  else
    qrnn_main<false><<<dim3(16, 8, 32), 512, 0, stream>>>((const unsigned short*)ws, x,
                                                          Vb, Fagg, Zagg);
  head_kernel<<<dim3(16, 32), 256, 0, stream>>>(x, W, V, Vb, Fagg, Zagg, h);
  mlp_atomic_kernel<<<dim3(16, 32, 4), 256, 0, stream>>>(h, W0, q0, 1024, 1024, 0);
  mlp_atomic_kernel<<<dim3(16, 32, 4), 256, 0, stream>>>(q0, W1, q1, 1024, 1024, 1);
  mlp_atomic_kernel<<<dim3(2, 32, 4), 256, 0, stream>>>(q1, W2, (float*)d_out, 1024, 128, 1);
}

// Round 7
// 609.479 us; speedup vs baseline: 1.0926x; 1.0926x over previous
//
#include <hip/hip_runtime.h>
#include <cstdint>
#include <cstddef>

// QRNN fused pipeline for MI355X (gfx950).
// B=32, S=2048, D_in=512, D_model=1024, D_mlp=1024, n_cls=128.
//
// ws layout (bytes): U bf16 [2048][1024] @0 (4MB) | Fagg @4MB | Zagg @6MB |
//   h @8MB | q0 @8MB+256K | q1 @8MB+512K | zero page @12MB (4KB) | xb bf16 @16MB (64MB)
//
//  1) prologue: pack_x + pack_u (LDS transpose) + bias preload + zero page, one kernel
//  2) qrnn_main<USE_BF>: 128x128 tile per (b, 128-step chunk, 64 d). Software-pipelined
//     K-loop: 16 stages of K=32; stage s+1 prefetched global->VGPR during stage s's
//     MFMAs; ds_write at stage top waits only own (landed) loads -> no global drain
//     at barriers. Single LDS buffer, chunk-column layout pitch 80B (<=2-way banks).
//     256 threads, launch_bounds(256,3): 64 acc AGPR + ~90 VGPR -> NO spill.
//  3) head: K-split o-gate + 16-chunk combine -> h
//  4) mlp x3 as K-split atomic GEMV (ReLU applied on consumer's input read)

typedef __attribute__((ext_vector_type(8))) short short8;
typedef __attribute__((ext_vector_type(4))) float f32x4;

#define ZERO_OFF_E 6291456u    // 12MB / 2 (bf16 elements)
#define XB_OFF_E   8388608u    // 16MB / 2

__device__ __forceinline__ unsigned short f2bf(float f) {
  unsigned int u = __float_as_uint(f);
  u += 0x7fffu + ((u >> 16) & 1u);
  return (unsigned short)(u >> 16);
}

__device__ __forceinline__ float sigmoidf_fast(float x) {
  return 1.f / (1.f + __expf(-x));
}
__device__ __forceinline__ float tanhf_fast(float x) {
  float a = fabsf(x);
  float e = __expf(-2.f * a);
  float t = (1.f - e) / (1.f + e);
  return copysignf(t, x);
}

// ---------------- prologue: pack_x + pack_u + bias preload + zero page ----------------
// grid 33409: [0,32768) pack_x; [32768,33280) pack_u; 33280..33407 init; 33408 zpg
__global__ void prologue_kernel(const float* __restrict__ x, const float* __restrict__ W,
                                const float* __restrict__ V,
                                const float* __restrict__ b0, const float* __restrict__ b1,
                                const float* __restrict__ b2,
                                unsigned short* __restrict__ xb, unsigned short* __restrict__ U,
                                float* __restrict__ q0, float* __restrict__ q1,
                                float* __restrict__ out, uint4* __restrict__ zpg) {
  __shared__ float T[64 * 65];
  const int bx = blockIdx.x;
  if (bx < 32768) {
    int gid = bx * 256 + threadIdx.x;
    float4 v = ((const float4*)x)[gid];
    ushort4 o;
    o.x = f2bf(v.x); o.y = f2bf(v.y); o.z = f2bf(v.z); o.w = f2bf(v.w);
    ((ushort4*)xb)[gid] = o;
  } else if (bx < 33280) {
    const int u = bx - 32768;
    const int j0 = (u & 31) * 64;
    const int k0 = (u >> 5) * 64;
    const int jl = threadIdx.x & 63;
    const int q  = threadIdx.x >> 6;
    const float* src = (k0 < 512) ? (W + (size_t)k0 * 3072) : (V + (size_t)(k0 - 512) * 3072);
#pragma unroll 4
    for (int i = 0; i < 16; ++i) {
      int kl = q * 16 + i;
      T[kl * 65 + jl] = src[(size_t)kl * 3072 + j0 + jl];
    }
    __syncthreads();
    const int kl = threadIdx.x & 63;
#pragma unroll 4
    for (int i = 0; i < 16; ++i) {
      int jj = q * 16 + i;
      U[(size_t)(j0 + jj) * 1024 + k0 + kl] = f2bf(T[kl * 65 + jj]);
    }
  } else if (bx < 33408) {
    int gid = (bx - 33280) * 256 + threadIdx.x;   // 32768
    q0[gid] = b0[gid & 1023];
    q1[gid] = b1[gid & 1023];
    if (gid < 4096) out[gid] = b2[gid & 127];
  } else {
    zpg[threadIdx.x] = make_uint4(0u, 0u, 0u, 0u);   // 4 KB zeros
  }
}

// ---------------- main: pipelined 128x128 MFMA tile + fused scan ----------------
// grid (16 dt, 16 cj, 32 b), block 256 (2x2 waves of 64x64)
// LDS stage buffer: A rows[0..128] pitch 80 @0 (10320 B); U rows[0..255] pitch 80 @10320.
// Row r of A = timestep s0-1+r, 4 chunks of 16B (8 bf16). U row r: col=r&127,half=r>>7.
template <bool USE_BF>
__global__ __launch_bounds__(256, 3) void qrnn_main(
    const unsigned short* __restrict__ wsb, const float* __restrict__ xf,
    const float* __restrict__ Vb,
    float* __restrict__ Fagg, float* __restrict__ Zagg) {
  __shared__ __align__(16) char smem[36864];

  const int dt = blockIdx.x;
  const int cj = blockIdx.y;
  const int b  = blockIdx.z;
  const int tid = threadIdx.x;
  const int lane = tid & 63;
  const int wid  = tid >> 6;
  const int wm = wid >> 1, wn = wid & 1;
  const int s0 = cj * 128;
  const int l15 = lane & 15, lc = lane >> 4;

  f32x4 acc[4][4];
#pragma unroll
  for (int i = 0; i < 4; ++i)
#pragma unroll
    for (int j = 0; j < 4; ++j) acc[i][j] = f32x4{0.f, 0.f, 0.f, 0.f};

  // ---- prefetch source offsets (bf16-element units rel. wsb; stage adds s*32) ----
  unsigned voffA[2];        // A chunks cw = tid, tid+256 -> row cw>>2 (0..127), chunk cw&3
  size_t offAF[2]; int zAF[2];   // fallback (fp32) variants
#pragma unroll
  for (int p = 0; p < 2; ++p) {
    int cw = tid + p * 256;
    int r = cw >> 2, c = cw & 3;
    int sg = s0 - 1 + r;
    voffA[p] = (sg < 0) ? (ZERO_OFF_E + (unsigned)(c * 8))
                        : (XB_OFF_E + (unsigned)(b * 2048 + sg) * 512u + (unsigned)(c * 8));
    zAF[p] = (sg < 0);
    offAF[p] = ((size_t)(b * 2048 + (sg < 0 ? 0 : sg)) << 9) + c * 8;
  }
  unsigned voffA3 = XB_OFF_E + (unsigned)(b * 2048 + s0 + 127) * 512u + (unsigned)((tid & 3) * 8);
  size_t offAF3 = ((size_t)(b * 2048 + s0 + 127) << 9) + (tid & 3) * 8;

  unsigned voffU[4];        // U chunks uw = tid + k*256 -> row uw>>2 (0..255), chunk uw&3
#pragma unroll
  for (int k = 0; k < 4; ++k) {
    int uw = tid + k * 256;
    int r = uw >> 2, c = uw & 3;
    int col = r & 127, half = r >> 7;
    int j = (col < 64) ? (dt * 64 + col) : (1024 + dt * 64 + (col - 64));
    voffU[k] = (unsigned)(j * 1024 + half * 512 + c * 8);
  }

  // ---- LDS write addresses ----
  unsigned wA[2], wU[4];
#pragma unroll
  for (int p = 0; p < 2; ++p) {
    int cw = tid + p * 256;
    wA[p] = (unsigned)((cw >> 2) * 80 + (cw & 3) * 16);
  }
  const unsigned wA3 = (unsigned)(128 * 80 + (tid & 3) * 16);
#pragma unroll
  for (int k = 0; k < 4; ++k) {
    int uw = tid + k * 256;
    wU[k] = (unsigned)(10320 + (uw >> 2) * 80 + (uw & 3) * 16);
  }

  // ---- fragment read offsets ----
  unsigned roA[2][4], roU[2][4];
#pragma unroll
  for (int h2 = 0; h2 < 2; ++h2) {
#pragma unroll
    for (int mt = 0; mt < 4; ++mt) {
      int rr = wm * 64 + l15 + mt * 16 + 1 - h2;
      roA[h2][mt] = (unsigned)(rr * 80 + lc * 16);
    }
#pragma unroll
    for (int nt = 0; nt < 4; ++nt) {
      int rrU = h2 * 128 + wn * 64 + l15 + nt * 16;
      roU[h2][nt] = (unsigned)(10320 + rrU * 80 + lc * 16);
    }
  }

  uint4 pA0, pA1, pA3, pU0, pU1, pU2, pU3;

  auto load_stage = [&](int s) {
    const unsigned short* cur = wsb + s * 32;
    if constexpr (USE_BF) {
      pA0 = *(const uint4*)(cur + voffA[0]);
      pA1 = *(const uint4*)(cur + voffA[1]);
      if (tid < 4) pA3 = *(const uint4*)(cur + voffA3);
    } else {
      const float* curf = xf + s * 32;
#pragma unroll
      for (int p = 0; p < 2; ++p) {
        uint4 v = make_uint4(0u, 0u, 0u, 0u);
        if (!zAF[p]) {
          float4 a0 = *(const float4*)(curf + offAF[p]);
          float4 a1 = *(const float4*)(curf + offAF[p] + 4);
          v.x = (unsigned)f2bf(a0.x) | ((unsigned)f2bf(a0.y) << 16);
          v.y = (unsigned)f2bf(a0.z) | ((unsigned)f2bf(a0.w) << 16);
          v.z = (unsigned)f2bf(a1.x) | ((unsigned)f2bf(a1.y) << 16);
          v.w = (unsigned)f2bf(a1.z) | ((unsigned)f2bf(a1.w) << 16);
        }
        if (p == 0) pA0 = v; else pA1 = v;
      }
      if (tid < 4) {
        float4 a0 = *(const float4*)(curf + offAF3);
        float4 a1 = *(const float4*)(curf + offAF3 + 4);
        pA3.x = (unsigned)f2bf(a0.x) | ((unsigned)f2bf(a0.y) << 16);
        pA3.y = (unsigned)f2bf(a0.z) | ((unsigned)f2bf(a0.w) << 16);
        pA3.z = (unsigned)f2bf(a1.x) | ((unsigned)f2bf(a1.y) << 16);
        pA3.w = (unsigned)f2bf(a1.z) | ((unsigned)f2bf(a1.w) << 16);
      }
    }
    pU0 = *(const uint4*)(cur + voffU[0]);
    pU1 = *(const uint4*)(cur + voffU[1]);
    pU2 = *(const uint4*)(cur + voffU[2]);
    pU3 = *(const uint4*)(cur + voffU[3]);
  };

  load_stage(0);

#pragma unroll 1
  for (int s = 0; s < 16; ++s) {
    __syncthreads();                    // readers of previous stage done
    // store stage s (waits only this wave's own landed loads, fine-grained vmcnt)
    *(uint4*)(smem + wA[0]) = pA0;
    *(uint4*)(smem + wA[1]) = pA1;
    if (tid < 4) *(uint4*)(smem + wA3) = pA3;
    *(uint4*)(smem + wU[0]) = pU0;
    *(uint4*)(smem + wU[1]) = pU1;
    *(uint4*)(smem + wU[2]) = pU2;
    *(uint4*)(smem + wU[3]) = pU3;
    __syncthreads();                    // publish (lgkm drain only)
    if (s < 15) load_stage(s + 1);      // async prefetch overlaps MFMAs below
    // ---- MFMA: 2 passes (h2: 0 = x[s]@W rows+1, 1 = x[s-1]@V rows+0) ----
#pragma unroll
    for (int h2 = 0; h2 < 2; ++h2) {
      short8 bfr[4];
#pragma unroll
      for (int nt = 0; nt < 4; ++nt)
        bfr[nt] = *(const short8*)(smem + roU[h2][nt]);
#pragma unroll
      for (int mt = 0; mt < 4; ++mt) {
        short8 afr = *(const short8*)(smem + roA[h2][mt]);
#pragma unroll
        for (int nt = 0; nt < 4; ++nt)
          acc[mt][nt] = __builtin_amdgcn_mfma_f32_16x16x32_bf16(afr, bfr[nt], acc[mt][nt], 0, 0, 0);
      }
    }
  }

  // ---- fused activations + scan (2 phases of 64 timesteps) ----
  float* fA   = (float*)smem;            // [64][68]
  float* tzA  = (float*)(smem + 17408);  // [64][68]
  float* segF = (float*)(smem + 34816);  // [4][64]
  float* segZ = (float*)(smem + 35840);  // [4][64]

  const int d = tid & 63;
  float vb[4];
#pragma unroll
  for (int nt = 0; nt < 4; ++nt)
    vb[nt] = Vb[wn * 1024 + dt * 64 + nt * 16 + l15];

  float F_run = 1.f, Z_run = 0.f;

  for (int ph = 0; ph < 2; ++ph) {
    __syncthreads();
    if (wm == ph) {
      float* dst = (wn == 0) ? fA : tzA;
#pragma unroll
      for (int mt = 0; mt < 4; ++mt)
#pragma unroll
        for (int nt = 0; nt < 4; ++nt)
#pragma unroll
          for (int rg = 0; rg < 4; ++rg) {
            int t = mt * 16 + ((lane >> 4) << 2) + rg;   // 0..63 phase-local
            int c = nt * 16 + l15;
            float v = acc[mt][nt][rg] + vb[nt];
            v = (wn == 0) ? sigmoidf_fast(v) : tanhf_fast(v);
            dst[t * 68 + c] = v;
          }
    }
    __syncthreads();
    {
      int seg = tid >> 6;
      float F = 1.f, Z = 0.f;
#pragma unroll 4
      for (int i = 0; i < 16; ++i) {
        int t = seg * 16 + i;
        float f  = fA[t * 68 + d];
        float tz = tzA[t * 68 + d];
        float z = (1.f - f) * tz;
        Z = f * Z + z;
        F *= f;
      }
      segF[seg * 64 + d] = F;
      segZ[seg * 64 + d] = Z;
    }
    __syncthreads();
    if (tid < 64) {
#pragma unroll
      for (int sgi = 0; sgi < 4; ++sgi) {
        float Fs = segF[sgi * 64 + tid], Zs = segZ[sgi * 64 + tid];
        Z_run = Fs * Z_run + Zs;
        F_run *= Fs;
      }
    }
  }
  if (tid < 64) {
    size_t o = (((size_t)b * 16 + cj) << 10) + dt * 64 + tid;
    Fagg[o] = F_run;
    Zagg[o] = Z_run;
  }
}

// ---------------- head: K-split o-gate + 16-chunk combine ----------------
// grid (16 dtile, 32 b), block 256 = 64 d x 4 k-segments
__global__ void head_kernel(const float* __restrict__ x, const float* __restrict__ W,
                            const float* __restrict__ V, const float* __restrict__ Vb,
                            const float* __restrict__ Fagg, const float* __restrict__ Zagg,
                            float* __restrict__ h) {
  __shared__ float red[4][64];
  const int dl = threadIdx.x & 63;
  const int w  = threadIdx.x >> 6;
  const int d = blockIdx.x * 64 + dl;
  const int b = blockIdx.y;

  const float* xl = x + ((size_t)b * 2048 + 2047) * 512;
  const float* xp = xl - 512;
  const float* Wc = W + 2048 + d;
  const float* Vc = V + 2048 + d;
  float po = 0.f;
  const int k0 = w * 128;
#pragma unroll 8
  for (int k = k0; k < k0 + 128; ++k) {
    po += xl[k] * Wc[(size_t)k * 3072];
    po += xp[k] * Vc[(size_t)k * 3072];
  }
  red[w][dl] = po;
  __syncthreads();
  if (w == 0) {
    po = red[0][dl] + red[1][dl] + red[2][dl] + red[3][dl] + Vb[2048 + d];
    float c = 0.f;
#pragma unroll
    for (int j = 0; j < 16; ++j) {
      size_t o = (((size_t)b * 16 + j) << 10) + d;
      c = Fagg[o] * c + Zagg[o];
    }
    h[((size_t)b << 10) + d] = c * sigmoidf_fast(po);
  }
}

// ---------------- MLP: K-split atomic GEMV (ReLU on input) ----------------
// grid (N/64, B, 4 ksplit), block 256 = 64 n x 4 waves
__global__ void mlp_atomic_kernel(const float* __restrict__ in, const float* __restrict__ Wt,
                                  float* __restrict__ out, int K, int N, int relu_in) {
  __shared__ float red[4][64];
  const int nl = threadIdx.x & 63;
  const int w  = threadIdx.x >> 6;
  const int n = blockIdx.x * 64 + nl;
  const int b = blockIdx.y;
  const int k0 = blockIdx.z * (K >> 2) + w * (K >> 4);
  const float* row = in + (size_t)b * K;
  const float* Wc = Wt + n;
  float s = 0.f;
#pragma unroll 8
  for (int k = k0; k < k0 + (K >> 4); ++k) {
    float v = row[k];
    if (relu_in) v = fmaxf(v, 0.f);
    s += v * Wc[(size_t)k * N];
  }
  red[w][nl] = s;
  __syncthreads();
  if (w == 0) {
    s = red[0][nl] + red[1][nl] + red[2][nl] + red[3][nl];
    atomicAdd(&out[(size_t)b * N + n], s);
  }
}

extern "C" void kernel_launch(void* const* d_in, const int* in_sizes, int n_in,
                              void* d_out, int out_size, void* d_ws, size_t ws_size,
                              hipStream_t stream) {
  const float* x  = (const float*)d_in[0];
  const float* W  = (const float*)d_in[1];
  const float* V  = (const float*)d_in[2];
  const float* Vb = (const float*)d_in[3];
  const float* W0 = (const float*)d_in[4];
  const float* b0 = (const float*)d_in[5];
  const float* W1 = (const float*)d_in[6];
  const float* b1 = (const float*)d_in[7];
  const float* W2 = (const float*)d_in[8];
  const float* b2 = (const float*)d_in[9];

  char* ws = (char*)d_ws;
  unsigned short* U = (unsigned short*)(ws);                              // 4 MiB
  float* Fagg = (float*)(ws + (size_t)4 * 1024 * 1024);                   // 2 MiB
  float* Zagg = (float*)(ws + (size_t)6 * 1024 * 1024);                   // 2 MiB
  float* h    = (float*)(ws + (size_t)8 * 1024 * 1024);                   // 128 KiB
  float* q0   = (float*)(ws + (size_t)8 * 1024 * 1024 + 256 * 1024);
  float* q1   = (float*)(ws + (size_t)8 * 1024 * 1024 + 512 * 1024);
  uint4* zpg  = (uint4*)(ws + (size_t)12 * 1024 * 1024);                  // 4 KiB zeros
  unsigned short* xb = (unsigned short*)(ws + (size_t)16 * 1024 * 1024);  // 64 MiB

  const size_t need_bf = (size_t)16 * 1024 * 1024 + (size_t)67108864;
  int use_bf = (ws_size >= need_bf) ? 1 : 0;   // constant across calls -> graph-safe

  prologue_kernel<<<33409, 256, 0, stream>>>(x, W, V, b0, b1, b2, xb, U, q0, q1,
                                             (float*)d_out, zpg);
  if (use_bf)
    qrnn_main<true><<<dim3(16, 16, 32), 256, 0, stream>>>((const unsigned short*)ws, x,
                                                          Vb, Fagg, Zagg);
  else
    qrnn_main<false><<<dim3(16, 16, 32), 256, 0, stream>>>((const unsigned short*)ws, x,
                                                           Vb, Fagg, Zagg);
  head_kernel<<<dim3(16, 32), 256, 0, stream>>>(x, W, V, Vb, Fagg, Zagg, h);
  mlp_atomic_kernel<<<dim3(16, 32, 4), 256, 0, stream>>>(h, W0, q0, 1024, 1024, 0);
  mlp_atomic_kernel<<<dim3(16, 32, 4), 256, 0, stream>>>(q0, W1, q1, 1024, 1024, 1);
  mlp_atomic_kernel<<<dim3(2, 32, 4), 256, 0, stream>>>(q1, W2, (float*)d_out, 1024, 128, 1);
}

// Round 8
// 605.671 us; speedup vs baseline: 1.0995x; 1.0063x over previous
//
#include <hip/hip_runtime.h>
#include <cstdint>
#include <cstddef>

// QRNN fused pipeline for MI355X (gfx950).
// B=32, S=2048, D_in=512, D_model=1024, D_mlp=1024, n_cls=128.
//
// ws layout (bytes): U bf16 [2048][1024] @0 (4MB) | Fagg @4MB | Zagg @6MB |
//   h @8MB | q0 @8MB+256K | q1 @8MB+512K | zero page @12MB (4KB) | xb bf16 @16MB (64MB)
//
//  1) prologue: pack_x (4 float4/thread) + pack_u (LDS transpose) + bias preload + zero page
//  2) qrnn_main<USE_BF>: 128x128 tile per (b, 128-step chunk, 64 d). Software-pipelined
//     K-loop: 16 stages of K=32; stage s+1 prefetched global->VGPR during stage s's
//     MFMAs. Stage LDS layout f(r,c)=r*64+16*((c+r+(r>>2))&3): every read & write
//     pattern is exactly 2 lanes/bank per 16-lane phase -> conflict-free (m136).
//  3) head: K-split o-gate + 16-chunk combine -> h
//  4) mlp x3 as K-split atomic GEMV (ReLU applied on consumer's input read)

typedef __attribute__((ext_vector_type(8))) short short8;
typedef __attribute__((ext_vector_type(4))) float f32x4;

#define ZERO_OFF_E 6291456u    // 12MB / 2 (bf16 elements)
#define XB_OFF_E   8388608u    // 16MB / 2
#define U_LDS_BASE 8256        // A stage = 129 rows * 64B

__device__ __forceinline__ unsigned short f2bf(float f) {
  unsigned int u = __float_as_uint(f);
  u += 0x7fffu + ((u >> 16) & 1u);
  return (unsigned short)(u >> 16);
}

__device__ __forceinline__ unsigned stage_addr(int r, int c) {
  return (unsigned)(r * 64 + (((c + r + (r >> 2)) & 3) << 4));
}

__device__ __forceinline__ float sigmoidf_fast(float x) {
  return 1.f / (1.f + __expf(-x));
}
__device__ __forceinline__ float tanhf_fast(float x) {
  float a = fabsf(x);
  float e = __expf(-2.f * a);
  float t = (1.f - e) / (1.f + e);
  return copysignf(t, x);
}

// ---------------- prologue ----------------
// grid 8833: [0,8192) pack_x (4 float4/thread); [8192,8704) pack_u; [8704,8832) init; 8832 zpg
__global__ void prologue_kernel(const float* __restrict__ x, const float* __restrict__ W,
                                const float* __restrict__ V,
                                const float* __restrict__ b0, const float* __restrict__ b1,
                                const float* __restrict__ b2,
                                unsigned short* __restrict__ xb, unsigned short* __restrict__ U,
                                float* __restrict__ q0, float* __restrict__ q1,
                                float* __restrict__ out, uint4* __restrict__ zpg) {
  __shared__ float T[64 * 65];
  const int bx = blockIdx.x;
  if (bx < 8192) {
    int base = bx * 1024 + threadIdx.x;
#pragma unroll
    for (int i = 0; i < 4; ++i) {
      int gid = base + i * 256;
      float4 v = ((const float4*)x)[gid];
      ushort4 o;
      o.x = f2bf(v.x); o.y = f2bf(v.y); o.z = f2bf(v.z); o.w = f2bf(v.w);
      ((ushort4*)xb)[gid] = o;
    }
  } else if (bx < 8704) {
    const int u = bx - 8192;
    const int j0 = (u & 31) * 64;
    const int k0 = (u >> 5) * 64;
    const int jl = threadIdx.x & 63;
    const int q  = threadIdx.x >> 6;
    const float* src = (k0 < 512) ? (W + (size_t)k0 * 3072) : (V + (size_t)(k0 - 512) * 3072);
#pragma unroll 4
    for (int i = 0; i < 16; ++i) {
      int kl = q * 16 + i;
      T[kl * 65 + jl] = src[(size_t)kl * 3072 + j0 + jl];
    }
    __syncthreads();
    const int kl = threadIdx.x & 63;
#pragma unroll 4
    for (int i = 0; i < 16; ++i) {
      int jj = q * 16 + i;
      U[(size_t)(j0 + jj) * 1024 + k0 + kl] = f2bf(T[kl * 65 + jj]);
    }
  } else if (bx < 8832) {
    int gid = (bx - 8704) * 256 + threadIdx.x;   // 32768
    q0[gid] = b0[gid & 1023];
    q1[gid] = b1[gid & 1023];
    if (gid < 4096) out[gid] = b2[gid & 127];
  } else {
    zpg[threadIdx.x] = make_uint4(0u, 0u, 0u, 0u);   // 4 KB zeros
  }
}

// ---------------- main: pipelined 128x128 MFMA tile + fused scan ----------------
// grid (16 dt, 16 cj, 32 b), block 256 (2x2 waves of 64x64)
// A stage: rows 0..128 (row r = timestep s0-1+r), 4 chunks of 16B. U stage: 256 rows
// (row = half*128 + col). Both placed via stage_addr (conflict-free).
template <bool USE_BF>
__global__ __launch_bounds__(256, 3) void qrnn_main(
    const unsigned short* __restrict__ wsb, const float* __restrict__ xf,
    const float* __restrict__ Vb,
    float* __restrict__ Fagg, float* __restrict__ Zagg) {
  __shared__ __align__(16) char smem[36864];

  const int dt = blockIdx.x;
  const int cj = blockIdx.y;
  const int b  = blockIdx.z;
  const int tid = threadIdx.x;
  const int lane = tid & 63;
  const int wid  = tid >> 6;
  const int wm = wid >> 1, wn = wid & 1;
  const int s0 = cj * 128;
  const int l15 = lane & 15, lc = lane >> 4;

  f32x4 acc[4][4];
#pragma unroll
  for (int i = 0; i < 4; ++i)
#pragma unroll
    for (int j = 0; j < 4; ++j) acc[i][j] = f32x4{0.f, 0.f, 0.f, 0.f};

  // ---- prefetch source offsets (bf16-element units rel. wsb; stage adds s*32) ----
  unsigned voffA[2];
  size_t offAF[2]; int zAF[2];
#pragma unroll
  for (int p = 0; p < 2; ++p) {
    int cw = tid + p * 256;
    int r = cw >> 2, c = cw & 3;
    int sg = s0 - 1 + r;
    voffA[p] = (sg < 0) ? (ZERO_OFF_E + (unsigned)(c * 8))
                        : (XB_OFF_E + (unsigned)(b * 2048 + sg) * 512u + (unsigned)(c * 8));
    zAF[p] = (sg < 0);
    offAF[p] = ((size_t)(b * 2048 + (sg < 0 ? 0 : sg)) << 9) + c * 8;
  }
  unsigned voffA3 = XB_OFF_E + (unsigned)(b * 2048 + s0 + 127) * 512u + (unsigned)((tid & 3) * 8);
  size_t offAF3 = ((size_t)(b * 2048 + s0 + 127) << 9) + (tid & 3) * 8;

  unsigned voffU[4];
#pragma unroll
  for (int k = 0; k < 4; ++k) {
    int uw = tid + k * 256;
    int r = uw >> 2, c = uw & 3;
    int col = r & 127, half = r >> 7;
    int j = (col < 64) ? (dt * 64 + col) : (1024 + dt * 64 + (col - 64));
    voffU[k] = (unsigned)(j * 1024 + half * 512 + c * 8);
  }

  // ---- LDS write addresses (conflict-free mapping) ----
  unsigned wA[2], wU[4];
#pragma unroll
  for (int p = 0; p < 2; ++p) {
    int cw = tid + p * 256;
    wA[p] = stage_addr(cw >> 2, cw & 3);
  }
  const unsigned wA3 = stage_addr(128, tid & 3);
#pragma unroll
  for (int k = 0; k < 4; ++k) {
    int uw = tid + k * 256;
    wU[k] = U_LDS_BASE + stage_addr(uw >> 2, uw & 3);
  }

  // ---- fragment read offsets ----
  unsigned roA[2][4], roU[2][4];
#pragma unroll
  for (int h2 = 0; h2 < 2; ++h2) {
#pragma unroll
    for (int mt = 0; mt < 4; ++mt) {
      int rr = wm * 64 + l15 + mt * 16 + 1 - h2;
      roA[h2][mt] = stage_addr(rr, lc);
    }
#pragma unroll
    for (int nt = 0; nt < 4; ++nt) {
      int rrU = h2 * 128 + wn * 64 + l15 + nt * 16;
      roU[h2][nt] = U_LDS_BASE + stage_addr(rrU, lc);
    }
  }

  uint4 pA0, pA1, pA3, pU0, pU1, pU2, pU3;

  auto load_stage = [&](int s) {
    const unsigned short* cur = wsb + s * 32;
    if constexpr (USE_BF) {
      pA0 = *(const uint4*)(cur + voffA[0]);
      pA1 = *(const uint4*)(cur + voffA[1]);
      if (tid < 4) pA3 = *(const uint4*)(cur + voffA3);
    } else {
      const float* curf = xf + s * 32;
#pragma unroll
      for (int p = 0; p < 2; ++p) {
        uint4 v = make_uint4(0u, 0u, 0u, 0u);
        if (!zAF[p]) {
          float4 a0 = *(const float4*)(curf + offAF[p]);
          float4 a1 = *(const float4*)(curf + offAF[p] + 4);
          v.x = (unsigned)f2bf(a0.x) | ((unsigned)f2bf(a0.y) << 16);
          v.y = (unsigned)f2bf(a0.z) | ((unsigned)f2bf(a0.w) << 16);
          v.z = (unsigned)f2bf(a1.x) | ((unsigned)f2bf(a1.y) << 16);
          v.w = (unsigned)f2bf(a1.z) | ((unsigned)f2bf(a1.w) << 16);
        }
        if (p == 0) pA0 = v; else pA1 = v;
      }
      if (tid < 4) {
        float4 a0 = *(const float4*)(curf + offAF3);
        float4 a1 = *(const float4*)(curf + offAF3 + 4);
        pA3.x = (unsigned)f2bf(a0.x) | ((unsigned)f2bf(a0.y) << 16);
        pA3.y = (unsigned)f2bf(a0.z) | ((unsigned)f2bf(a0.w) << 16);
        pA3.z = (unsigned)f2bf(a1.x) | ((unsigned)f2bf(a1.y) << 16);
        pA3.w = (unsigned)f2bf(a1.z) | ((unsigned)f2bf(a1.w) << 16);
      }
    }
    pU0 = *(const uint4*)(cur + voffU[0]);
    pU1 = *(const uint4*)(cur + voffU[1]);
    pU2 = *(const uint4*)(cur + voffU[2]);
    pU3 = *(const uint4*)(cur + voffU[3]);
  };

  load_stage(0);

#pragma unroll 1
  for (int s = 0; s < 16; ++s) {
    __syncthreads();                    // readers of previous stage done
    *(uint4*)(smem + wA[0]) = pA0;
    *(uint4*)(smem + wA[1]) = pA1;
    if (tid < 4) *(uint4*)(smem + wA3) = pA3;
    *(uint4*)(smem + wU[0]) = pU0;
    *(uint4*)(smem + wU[1]) = pU1;
    *(uint4*)(smem + wU[2]) = pU2;
    *(uint4*)(smem + wU[3]) = pU3;
    __syncthreads();                    // publish (lgkm drain only)
    if (s < 15) load_stage(s + 1);      // prefetch overlaps MFMAs below
#pragma unroll
    for (int h2 = 0; h2 < 2; ++h2) {
      short8 bfr[4];
#pragma unroll
      for (int nt = 0; nt < 4; ++nt)
        bfr[nt] = *(const short8*)(smem + roU[h2][nt]);
#pragma unroll
      for (int mt = 0; mt < 4; ++mt) {
        short8 afr = *(const short8*)(smem + roA[h2][mt]);
#pragma unroll
        for (int nt = 0; nt < 4; ++nt)
          acc[mt][nt] = __builtin_amdgcn_mfma_f32_16x16x32_bf16(afr, bfr[nt], acc[mt][nt], 0, 0, 0);
      }
    }
  }

  // ---- fused activations + scan (2 phases of 64 timesteps) ----
  float* fA   = (float*)smem;            // [64][68]
  float* tzA  = (float*)(smem + 17408);  // [64][68]
  float* segF = (float*)(smem + 34816);  // [4][64]
  float* segZ = (float*)(smem + 35840);  // [4][64]

  const int d = tid & 63;
  float vb[4];
#pragma unroll
  for (int nt = 0; nt < 4; ++nt)
    vb[nt] = Vb[wn * 1024 + dt * 64 + nt * 16 + l15];

  float F_run = 1.f, Z_run = 0.f;

  for (int ph = 0; ph < 2; ++ph) {
    __syncthreads();
    if (wm == ph) {
      float* dst = (wn == 0) ? fA : tzA;
#pragma unroll
      for (int mt = 0; mt < 4; ++mt)
#pragma unroll
        for (int nt = 0; nt < 4; ++nt)
#pragma unroll
          for (int rg = 0; rg < 4; ++rg) {
            int t = mt * 16 + ((lane >> 4) << 2) + rg;   // 0..63 phase-local
            int c = nt * 16 + l15;
            float v = acc[mt][nt][rg] + vb[nt];
            v = (wn == 0) ? sigmoidf_fast(v) : tanhf_fast(v);
            dst[t * 68 + c] = v;
          }
    }
    __syncthreads();
    {
      int seg = tid >> 6;
      float F = 1.f, Z = 0.f;
#pragma unroll 4
      for (int i = 0; i < 16; ++i) {
        int t = seg * 16 + i;
        float f  = fA[t * 68 + d];
        float tz = tzA[t * 68 + d];
        float z = (1.f - f) * tz;
        Z = f * Z + z;
        F *= f;
      }
      segF[seg * 64 + d] = F;
      segZ[seg * 64 + d] = Z;
    }
    __syncthreads();
    if (tid < 64) {
#pragma unroll
      for (int sgi = 0; sgi < 4; ++sgi) {
        float Fs = segF[sgi * 64 + tid], Zs = segZ[sgi * 64 + tid];
        Z_run = Fs * Z_run + Zs;
        F_run *= Fs;
      }
    }
  }
  if (tid < 64) {
    size_t o = (((size_t)b * 16 + cj) << 10) + dt * 64 + tid;
    Fagg[o] = F_run;
    Zagg[o] = Z_run;
  }
}

// ---------------- head: K-split o-gate + 16-chunk combine ----------------
// grid (16 dtile, 32 b), block 256 = 64 d x 4 k-segments
__global__ void head_kernel(const float* __restrict__ x, const float* __restrict__ W,
                            const float* __restrict__ V, const float* __restrict__ Vb,
                            const float* __restrict__ Fagg, const float* __restrict__ Zagg,
                            float* __restrict__ h) {
  __shared__ float red[4][64];
  const int dl = threadIdx.x & 63;
  const int w  = threadIdx.x >> 6;
  const int d = blockIdx.x * 64 + dl;
  const int b = blockIdx.y;

  const float* xl = x + ((size_t)b * 2048 + 2047) * 512;
  const float* xp = xl - 512;
  const float* Wc = W + 2048 + d;
  const float* Vc = V + 2048 + d;
  float po = 0.f;
  const int k0 = w * 128;
#pragma unroll 8
  for (int k = k0; k < k0 + 128; ++k) {
    po += xl[k] * Wc[(size_t)k * 3072];
    po += xp[k] * Vc[(size_t)k * 3072];
  }
  red[w][dl] = po;
  __syncthreads();
  if (w == 0) {
    po = red[0][dl] + red[1][dl] + red[2][dl] + red[3][dl] + Vb[2048 + d];
    float c = 0.f;
#pragma unroll
    for (int j = 0; j < 16; ++j) {
      size_t o = (((size_t)b * 16 + j) << 10) + d;
      c = Fagg[o] * c + Zagg[o];
    }
    h[((size_t)b << 10) + d] = c * sigmoidf_fast(po);
  }
}

// ---------------- MLP: K-split atomic GEMV (ReLU on input) ----------------
// grid (N/64, B, 4 ksplit), block 256 = 64 n x 4 waves
__global__ void mlp_atomic_kernel(const float* __restrict__ in, const float* __restrict__ Wt,
                                  float* __restrict__ out, int K, int N, int relu_in) {
  __shared__ float red[4][64];
  const int nl = threadIdx.x & 63;
  const int w  = threadIdx.x >> 6;
  const int n = blockIdx.x * 64 + nl;
  const int b = blockIdx.y;
  const int k0 = blockIdx.z * (K >> 2) + w * (K >> 4);
  const float* row = in + (size_t)b * K;
  const float* Wc = Wt + n;
  float s = 0.f;
#pragma unroll 8
  for (int k = k0; k < k0 + (K >> 4); ++k) {
    float v = row[k];
    if (relu_in) v = fmaxf(v, 0.f);
    s += v * Wc[(size_t)k * N];
  }
  red[w][nl] = s;
  __syncthreads();
  if (w == 0) {
    s = red[0][nl] + red[1][nl] + red[2][nl] + red[3][nl];
    atomicAdd(&out[(size_t)b * N + n], s);
  }
}

extern "C" void kernel_launch(void* const* d_in, const int* in_sizes, int n_in,
                              void* d_out, int out_size, void* d_ws, size_t ws_size,
                              hipStream_t stream) {
  const float* x  = (const float*)d_in[0];
  const float* W  = (const float*)d_in[1];
  const float* V  = (const float*)d_in[2];
  const float* Vb = (const float*)d_in[3];
  const float* W0 = (const float*)d_in[4];
  const float* b0 = (const float*)d_in[5];
  const float* W1 = (const float*)d_in[6];
  const float* b1 = (const float*)d_in[7];
  const float* W2 = (const float*)d_in[8];
  const float* b2 = (const float*)d_in[9];

  char* ws = (char*)d_ws;
  unsigned short* U = (unsigned short*)(ws);                              // 4 MiB
  float* Fagg = (float*)(ws + (size_t)4 * 1024 * 1024);                   // 2 MiB
  float* Zagg = (float*)(ws + (size_t)6 * 1024 * 1024);                   // 2 MiB
  float* h    = (float*)(ws + (size_t)8 * 1024 * 1024);                   // 128 KiB
  float* q0   = (float*)(ws + (size_t)8 * 1024 * 1024 + 256 * 1024);
  float* q1   = (float*)(ws + (size_t)8 * 1024 * 1024 + 512 * 1024);
  uint4* zpg  = (uint4*)(ws + (size_t)12 * 1024 * 1024);                  // 4 KiB zeros
  unsigned short* xb = (unsigned short*)(ws + (size_t)16 * 1024 * 1024);  // 64 MiB

  const size_t need_bf = (size_t)16 * 1024 * 1024 + (size_t)67108864;
  int use_bf = (ws_size >= need_bf) ? 1 : 0;   // constant across calls -> graph-safe

  prologue_kernel<<<8833, 256, 0, stream>>>(x, W, V, b0, b1, b2, xb, U, q0, q1,
                                            (float*)d_out, zpg);
  if (use_bf)
    qrnn_main<true><<<dim3(16, 16, 32), 256, 0, stream>>>((const unsigned short*)ws, x,
                                                          Vb, Fagg, Zagg);
  else
    qrnn_main<false><<<dim3(16, 16, 32), 256, 0, stream>>>((const unsigned short*)ws, x,
                                                           Vb, Fagg, Zagg);
  head_kernel<<<dim3(16, 32), 256, 0, stream>>>(x, W, V, Vb, Fagg, Zagg, h);
  mlp_atomic_kernel<<<dim3(16, 32, 4), 256, 0, stream>>>(h, W0, q0, 1024, 1024, 0);
  mlp_atomic_kernel<<<dim3(16, 32, 4), 256, 0, stream>>>(q0, W1, q1, 1024, 1024, 1);
  mlp_atomic_kernel<<<dim3(2, 32, 4), 256, 0, stream>>>(q1, W2, (float*)d_out, 1024, 128, 1);
}